// Round 9
// baseline (500.444 us; speedup 1.0000x reference)
//
#include <hip/hip_runtime.h>
#include <math.h>

// SSDLite post-processing, round 16 = round 15 (361us nms) with 128-candidate
// tiles (2 candidates per lane) -> exactly ONE tile-pair per CAP=256 round.
//  - Dense loop: per-tile overhead (5x ds_read_b128 + fmax-combine + ballot +
//    loop ctl ~15 instr per 4 kept) amortizes over 2 candidates: ~10% less
//    dense W, which is ~2/3 of total W.
//  - Barriers: scan barriers per round 4 -> 2 (one resolve pair); fewer
//    convoy stalls (the ~35% issue-idle is barrier convoys + latency).
//  - Resolve: A-slot global positions (base..base+63) all precede B-slots
//    (base+64..base+127) in sorted order -> pop MA to empty then MB; each
//    kept prunes BOTH masks (one extra ballot). Keep sequence bit-exact:
//    same iou_val expression/orientation, masks are pruning-only.
//  - Catch-up: wave 1 tests both slots vs keeps [nk0,nk1).
// Structure/numerics otherwise identical to round 15: 2-wave coop class
// blocks (grid=batch*20, 128 thr, 7.4KB LDS, 16 blk/CU = 32 waves phase-1),
// XCD swizzle, float-max dense accumulator, M-refilter resolve, exact 2x-fma
// IoU predicate, same sort keys.

#define NCLS 21
#define TOPK 200
#define NPRI 3000
#define ELTS 47            // ceil(3000/64)
#define CONF_T 0.01f
#define MHI 0.45f
#define MLO 1.490116119384765625e-08f   // 2^-26 == ulp(0.45f)/2
#define CAP 256            // sort/batch capacity
#define NBUCK 256          // histogram buckets (224 used)
#define NUSED 224
#define BITS_BASE 0x3C000000u           // bits(2^-7); 0.01 > 2^-7
#define BSHIFT 18

__device__ __forceinline__ float rdlf(float v, int l) {
  return __int_as_float(__builtin_amdgcn_readlane(__float_as_int(v), l));
}

// IoU suppression VALUE: >0 means suppressed. EXACT reference numerics
// (2x fma, MLO half-ulp nudge); 'a' = kept-box area everywhere.
__device__ __forceinline__ float iou_val(const float4 k, const float a,
                                         const float4 b, const float carea) {
  float ltx = fmaxf(k.x, b.x), lty = fmaxf(k.y, b.y);
  float rbx = fminf(k.z, b.z), rby = fminf(k.w, b.w);
  float iw = fmaxf(rbx - ltx, 0.0f), ih = fmaxf(rby - lty, 0.0f);
  float inter = iw * ih;
  float uni = (a + carea) - inter;
  return fmaf(-MLO, uni, fmaf(-MHI, uni, inter));
}

// M-refilter keep-resolution over TWO slots per lane. All A positions
// precede all B positions in sorted order, so: pop MA until empty, then MB.
// Each kept box prunes both masks. Identical kept sequence to sequential.
__device__ __forceinline__ int resolve_tile2(
    unsigned long long MA, unsigned long long MB,
    const float4 bxA, const float caA, const unsigned int bitsA,
    const float4 bxB, const float caB, const unsigned int bitsB,
    const int lane, int nk,
    float4* kbox, float* karr, float* kscore) {
  while ((MA | MB) && nk < TOPK) {
    const bool fromA = (MA != 0ull);          // wave-uniform
    float4 nb; float nar; unsigned int nbits;
    if (fromA) {
      const int ls = (int)__builtin_ctzll(MA);
      nb = make_float4(rdlf(bxA.x, ls), rdlf(bxA.y, ls),
                       rdlf(bxA.z, ls), rdlf(bxA.w, ls));
      nar = rdlf(caA, ls);
      nbits = (unsigned int)__builtin_amdgcn_readlane((int)bitsA, ls);
      MA &= ~(1ull << ls);
    } else {
      const int ls = (int)__builtin_ctzll(MB);
      nb = make_float4(rdlf(bxB.x, ls), rdlf(bxB.y, ls),
                       rdlf(bxB.z, ls), rdlf(bxB.w, ls));
      nar = rdlf(caB, ls);
      nbits = (unsigned int)__builtin_amdgcn_readlane((int)bitsB, ls);
      MB &= ~(1ull << ls);
    }
    if (lane == 0) {
      kbox[nk]   = nb;
      karr[nk]   = nar;
      kscore[nk] = __uint_as_float(nbits);
    }
    ++nk;
    MA &= ~__ballot(iou_val(nb, nar, bxA, caA) > 0.0f);
    MB &= ~__ballot(iou_val(nb, nar, bxB, caB) > 0.0f);
  }
  return nk;
}

__global__ void decode_kernel(const float* __restrict__ loc,
                              const float* __restrict__ priors,
                              float4* __restrict__ wsbox,
                              float* __restrict__ out) {
  const int b = blockIdx.x;
  // class-0 rows are all zeros
  float* o0 = out + (size_t)b * NCLS * TOPK * 5;
  for (int i = threadIdx.x; i < TOPK * 5; i += 256) o0[i] = 0.0f;
  for (int j = threadIdx.x; j < NPRI; j += 256) {
    const float4 l4 = *(const float4*)(loc + ((size_t)b * NPRI + j) * 4);
    const float4 p  = *(const float4*)(priors + (size_t)j * 4);
    float cx = p.x + (l4.x * 0.1f) * p.z;
    float cy = p.y + (l4.y * 0.1f) * p.w;
    float bw = p.z * expf(l4.z * 0.2f);
    float bh = p.w * expf(l4.w * 0.2f);
    wsbox[(size_t)b * NPRI + j] = make_float4(cx - bw * 0.5f, cy - bh * 0.5f,
                                              cx + bw * 0.5f, cy + bh * 0.5f);
  }
}

__global__ __launch_bounds__(128, 8) void ssd_nms_kernel(
    const float* __restrict__ conf, const float4* __restrict__ wsbox,
    float* __restrict__ out, int nbatch) {
  const int blk = blockIdx.x;
  int b, c1;
  if ((nbatch & 7) == 0) {
    // XCD swizzle: image b's 20 class-blocks land on XCD b&7 -> the image's
    // conf slab + wsbox stay in one XCD's L2.
    const int xcd  = blk & 7;
    const int rest = blk >> 3;
    b  = (rest / 20) * 8 + xcd;
    c1 = rest % 20;
  } else {
    b  = blk / 20;
    c1 = blk % 20;
  }
  const int c    = 1 + c1;            // class in [1,20]
  const int tid  = threadIdx.x;
  const int lane = tid & 63;
  const int w    = tid >> 6;          // wave in block (2 waves, one class)

  __shared__ unsigned long long skey[CAP];       // 2,048 B sort buf
  __shared__ unsigned int hist[NBUCK / 2];       //   512 B packed u16 hist
  __shared__ float4 kbox[TOPK];                  // 3,200 B kept boxes
  __shared__ alignas(16) float karr[TOPK];       //   800 B kept areas
  __shared__ float  kscore[TOPK];                //   800 B kept scores
  __shared__ int sh_nk;                          // block-consistent kept count
  __shared__ int sh_ctr;                         // compaction position counter

  for (int i = tid; i < NBUCK / 2; i += 128) hist[i] = 0u;
  if (tid == 0) sh_nk = 0;
  __syncthreads();

  const float* myF = conf + (size_t)b * NPRI * NCLS + c;

  // ---- histogram over thresholded score bits, j-space split by wave ----
  for (int k = w; k < ELTS; k += 2) {
    const int j = k * 64 + lane;
    unsigned int bits = 0u;
    if (j < NPRI) {
      float s = myF[(size_t)j * NCLS];
      bits = (s > CONF_T) ? __float_as_uint(s) : 0u;
    }
    if (bits) {
      unsigned int bu = (bits - BITS_BASE) >> BSHIFT;   // 8..223
      atomicAdd(&hist[bu >> 1], 1u << ((bu & 1) * 16));
    }
  }
  __syncthreads();

  float* obase = out + ((size_t)b * NCLS + c) * (TOPK * 5);
  const float4* mybox = wsbox + (size_t)b * NPRI;
  int cutHiB = NUSED;

  for (;;) {
    // round head: sh_nk last written before a barrier -> both waves agree
    if (sh_nk >= TOPK || cutHiB <= 0) break;

    // ---- pick batch (both waves redundantly, identical result) ----
    int sl = 0;
#pragma unroll
    for (int t = 0; t < 4; ++t) {
      int bu = lane * 4 + t;
      if (bu < cutHiB) sl += (int)((hist[bu >> 1] >> ((bu & 1) * 16)) & 0xFFFFu);
    }
    int suf = sl;
#pragma unroll
    for (int d = 1; d < 64; d <<= 1) {
      int v = __shfl_down(suf, d, 64);
      if (lane + d < 64) suf += v;
    }
    unsigned long long m = __ballot(suf <= CAP);
    int Ls = (m != 0ull) ? __builtin_ctzll(m) : 63;
    int cutLoB = Ls * 4;
    if (cutLoB >= cutHiB) cutLoB = (cutHiB - 1) & ~3;   // degenerate, P~0
    const unsigned int loBits = BITS_BASE + ((unsigned)cutLoB << BSHIFT);
    const unsigned int hiBits = BITS_BASE + ((unsigned)cutHiB << BSHIFT);

    // ---- compact batch members; position via shared atomic (order is
    //      irrelevant: keys unique, sort follows) ----
    if (tid == 0) sh_ctr = 0;
    for (int t = tid; t < CAP; t += 128) skey[t] = 0ull;
    __syncthreads();

    for (int k = w; k < ELTS; k += 2) {
      const int j = k * 64 + lane;
      unsigned int bits = 0u;
      if (j < NPRI) {
        float s = myF[(size_t)j * NCLS];
        bits = (s > CONF_T) ? __float_as_uint(s) : 0u;
      }
      bool sel = (bits >= loBits) && (bits < hiBits);
      unsigned long long bm = __ballot(sel);
      int cnt = (int)__popcll(bm);
      int wb = 0;
      if (lane == 0 && cnt) wb = atomicAdd(&sh_ctr, cnt);
      wb = __builtin_amdgcn_readfirstlane(wb);
      if (sel) {
        int pos = wb + (int)__popcll(bm & ((1ull << lane) - 1ull));
        if (pos < CAP)
          skey[pos] = ((unsigned long long)bits << 12) | (unsigned)(4095 - j);
      }
    }
    __syncthreads();
    int Nc = sh_ctr;
    if (Nc > CAP) Nc = CAP;

    if (Nc > 0) {
      // ---- bitonic sort descending, 128 threads, 1 pair/thread/pass.
      //      jj<=64 passes stay inside one wave's half; only jj=128 crosses
      //      waves -> 2 barriers mid-sort + 1 post-sort (round-10 fix). ----
      for (int kk = 2; kk <= CAP; kk <<= 1) {
        for (int jj = kk >> 1; jj > 0; jj >>= 1) {
          if (jj == 128) __syncthreads();   // about to read across halves
          int i = ((tid & ~(jj - 1)) << 1) | (tid & (jj - 1));
          int ixj = i | jj;
          unsigned long long a = skey[i], d = skey[ixj];
          bool up = (i & kk) == 0;
          if (up ? (a < d) : (a > d)) { skey[i] = d; skey[ixj] = a; }
          if (jj == 128) __syncthreads();   // cross-half writes visible
          else __threadfence_block();       // same-wave DS in-order
        }
      }
      __syncthreads();

      // ---- single tile-pair scan: wave w owns candidates w*128..w*128+127
      //      (2 slots/lane); dense-test vs kept snapshot in parallel ----
      const int nk0 = sh_nk;              // post-barrier consistent snapshot

      const int pA = w * 128 + lane;
      const int pB = pA + 64;
      const bool vA = pA < Nc, vB = pB < Nc;
      unsigned long long keyA = vA ? skey[pA] : 0ull;
      unsigned long long keyB = vB ? skey[pB] : 0ull;
      unsigned int bitsA = (unsigned int)(keyA >> 12);
      unsigned int bitsB = (unsigned int)(keyB >> 12);
      int jA = 4095 - (int)(keyA & 4095ull);
      int jB = 4095 - (int)(keyB & 4095ull);
      float4 bxA = mybox[vA ? jA : 0];
      float4 bxB = mybox[vB ? jB : 0];
      float caA = (bxA.z - bxA.x) * (bxA.w - bxA.y);
      float caB = (bxB.z - bxB.x) * (bxB.w - bxB.y);

      // dense vs kept[0..nk0): float-max accumulators, both slots
      float fmA = vA ? -1.0f : 1.0f;      // padding pre-suppressed
      float fmB = vB ? -1.0f : 1.0f;
      int s = 0;
      for (; s + 3 < nk0; s += 4) {
        float4 k0 = kbox[s];     float4 k1 = kbox[s + 1];
        float4 k2 = kbox[s + 2]; float4 k3 = kbox[s + 3];
        float4 ar = *(const float4*)&karr[s];   // one ds_read_b128
        float a01 = fmaxf(iou_val(k0, ar.x, bxA, caA),
                          iou_val(k1, ar.y, bxA, caA));
        float a23 = fmaxf(iou_val(k2, ar.z, bxA, caA),
                          iou_val(k3, ar.w, bxA, caA));
        fmA = fmaxf(fmA, fmaxf(a01, a23));
        float b01 = fmaxf(iou_val(k0, ar.x, bxB, caB),
                          iou_val(k1, ar.y, bxB, caB));
        float b23 = fmaxf(iou_val(k2, ar.z, bxB, caB),
                          iou_val(k3, ar.w, bxB, caB));
        fmB = fmaxf(fmB, fmaxf(b01, b23));
        if (__ballot(fmA > 0.0f && fmB > 0.0f) == ~0ull) { s = nk0; break; }
      }
      for (; s < nk0; ++s) {
        float4 kk = kbox[s]; float ka = karr[s];
        fmA = fmaxf(fmA, iou_val(kk, ka, bxA, caA));
        fmB = fmaxf(fmB, iou_val(kk, ka, bxB, caB));
      }
      unsigned long long sA = __ballot(fmA > 0.0f);
      unsigned long long sB = __ballot(fmB > 0.0f);

      if (w == 0) {   // resolve candidates 0..127 (writes kbox[nk0..),
                      // disjoint from wave 1's reads of kbox[0..nk0))
        int nk = resolve_tile2(~sA, ~sB, bxA, caA, bitsA, bxB, caB, bitsB,
                               lane, nk0, kbox, karr, kscore);
        if (lane == 0) sh_nk = nk;
      }
      __syncthreads();
      if (w == 1) {   // catch-up vs keeps [nk0,nk1), then resolve 128..255
        const int nk1 = sh_nk;
        for (int s2 = nk0; s2 < nk1; ++s2) {
          float4 kk = kbox[s2]; float ka = karr[s2];
          sA |= __ballot(iou_val(kk, ka, bxA, caA) > 0.0f);
          sB |= __ballot(iou_val(kk, ka, bxB, caB) > 0.0f);
          if ((sA & sB) == ~0ull) break;
        }
        int nk = resolve_tile2(~sA, ~sB, bxA, caA, bitsA, bxB, caB, bitsB,
                               lane, nk1, kbox, karr, kscore);
        if (lane == 0) sh_nk = nk;
      }
      __syncthreads();
    }
    cutHiB = cutLoB;
  }

  // ---- coalesced output dump: rows (score,x1,y1,x2,y2), zeros past nk ----
  __syncthreads();
  const int nkf = sh_nk;
  const float* kbf = (const float*)&kbox[0];
  for (int i = tid; i < TOPK * 5; i += 128) {
    int r = i / 5;
    int col = i - r * 5;
    float v = 0.0f;
    if (r < nkf) v = (col == 0) ? kscore[r] : kbf[r * 4 + (col - 1)];
    obase[i] = v;
  }
}

extern "C" void kernel_launch(void* const* d_in, const int* in_sizes, int n_in,
                              void* d_out, int out_size, void* d_ws, size_t ws_size,
                              hipStream_t stream) {
  const float* loc    = (const float*)d_in[0];
  const float* conf   = (const float*)d_in[1];
  const float* priors = (const float*)d_in[2];
  float* out = (float*)d_out;
  float4* wsbox = (float4*)d_ws;      // batch*3000*16 B = 12.3 MB

  const int batch = in_sizes[0] / (NPRI * 4);
  hipLaunchKernelGGL(decode_kernel, dim3(batch), dim3(256), 0, stream,
                     loc, priors, wsbox, out);
  hipLaunchKernelGGL(ssd_nms_kernel, dim3(batch * 20), dim3(128), 0, stream,
                     conf, wsbox, out, batch);
}

// Round 10
// 421.231 us; speedup vs baseline: 1.1880x; 1.1880x over previous
//
#include <hip/hip_runtime.h>
#include <math.h>

// SSDLite post-processing, round 17 = round 15 (361us nms, best known) with
// the decode kernel FUSED into the NMS kernel (single launch).
// Round-16 post-mortem: 2-slot tiles REVERTED -- WRITE_SIZE doubled 20->40MB
// at pinned VGPR=32 (scratch spill in the hot loop) and the whole-tile early
// exit weakened (needs both slots dead). Round 15 stands.
// Why fuse: across all rounds, total exceeds the nms dispatch by a constant
// 70-79us (431 vs 361) while decode moves only ~29MB (~6us of BW). Whether
// that gap is decode time or dual-launch dependency cost, fusion removes it:
//  - decode-on-gather: candidate boxes decoded inline at tile load (loc[j]
//    16B gather + L2-hot priors[j] + 2x expf, bit-identical op order to the
//    old decode kernel). ~3000 decodes/class = +1-2% W. Kept boxes stay in
//    LDS (kbox) -> resolve/catch-up never re-decode.
//  - wsbox workspace eliminated (no 12.3MB write + 12.3MB gather-back).
//  - class-0 zeroing moves to the c1==0 blocks (1000 floats, coalesced).
// Everything else byte-identical to round 15: 2-wave coop class blocks
// (grid=batch*20, 128 thr, 7.4KB LDS, 16 blk/CU = 32 waves phase-1), XCD
// swizzle, histogram-batched sorted scan (CAP=256), 128-thread bitonic sort
// (2 mid + 1 post barrier), float-max dense accumulator w/ karr ds_read_b128,
// M-refilter resolve, exact 2x-fma IoU predicate.

#define NCLS 21
#define TOPK 200
#define NPRI 3000
#define ELTS 47            // ceil(3000/64)
#define CONF_T 0.01f
#define MHI 0.45f
#define MLO 1.490116119384765625e-08f   // 2^-26 == ulp(0.45f)/2
#define CAP 256            // sort/batch capacity
#define NBUCK 256          // histogram buckets (224 used)
#define NUSED 224
#define BITS_BASE 0x3C000000u           // bits(2^-7); 0.01 > 2^-7
#define BSHIFT 18

__device__ __forceinline__ float rdlf(float v, int l) {
  return __int_as_float(__builtin_amdgcn_readlane(__float_as_int(v), l));
}

// IoU suppression VALUE: >0 means suppressed. EXACT reference numerics
// (2x fma, MLO half-ulp nudge); 'a' = kept-box area everywhere.
__device__ __forceinline__ float iou_val(const float4 k, const float a,
                                         const float4 b, const float carea) {
  float ltx = fmaxf(k.x, b.x), lty = fmaxf(k.y, b.y);
  float rbx = fminf(k.z, b.z), rby = fminf(k.w, b.w);
  float iw = fmaxf(rbx - ltx, 0.0f), ih = fmaxf(rby - lty, 0.0f);
  float inter = iw * ih;
  float uni = (a + carea) - inter;
  return fmaf(-MLO, uni, fmaf(-MHI, uni, inter));
}

__device__ __forceinline__ bool iou_sup(const float4 k, const float a,
                                        const float4 b, const float carea) {
  return iou_val(k, a, b, carea) > 0.0f;
}

// M-refilter keep-resolution (round 15). Pop lowest survivor (guaranteed
// keepable), broadcast, prune M by one parallel iou. Sequential-identical.
__device__ __forceinline__ int resolve_tile(
    unsigned long long smask, const float4 bx, const float carea,
    const unsigned int bits, const int lane, int nk,
    float4* kbox, float* karr, float* kscore) {
  unsigned long long M = ~smask;
  while (M && nk < TOPK) {
    const int ls = (int)__builtin_ctzll(M);
    const float sx1 = rdlf(bx.x, ls), sy1 = rdlf(bx.y, ls);
    const float sx2 = rdlf(bx.z, ls), sy2 = rdlf(bx.w, ls);
    const float sar = rdlf(carea, ls);
    const unsigned int sbits =
        (unsigned int)__builtin_amdgcn_readlane((int)bits, ls);
    const float4 nb = make_float4(sx1, sy1, sx2, sy2);
    if (lane == 0) {
      kbox[nk]   = nb;
      karr[nk]   = sar;
      kscore[nk] = __uint_as_float(sbits);
    }
    ++nk;
    // prune remaining survivors by the newly kept box (self included: iou=1)
    M &= ~__ballot(iou_val(nb, sar, bx, carea) > 0.0f);
    M &= ~(1ull << ls);
  }
  return nk;
}

__global__ __launch_bounds__(128, 8) void ssd_nms_kernel(
    const float* __restrict__ loc, const float* __restrict__ conf,
    const float* __restrict__ priors, float* __restrict__ out, int nbatch) {
  const int blk = blockIdx.x;
  int b, c1;
  if ((nbatch & 7) == 0) {
    // XCD swizzle: image b's 20 class-blocks land on XCD b&7 -> the image's
    // conf/loc slabs stay in one XCD's L2.
    const int xcd  = blk & 7;
    const int rest = blk >> 3;
    b  = (rest / 20) * 8 + xcd;
    c1 = rest % 20;
  } else {
    b  = blk / 20;
    c1 = blk % 20;
  }
  const int c    = 1 + c1;            // class in [1,20]
  const int tid  = threadIdx.x;
  const int lane = tid & 63;
  const int w    = tid >> 6;          // wave in block (2 waves, one class)

  __shared__ unsigned long long skey[CAP];       // 2,048 B sort buf
  __shared__ unsigned int hist[NBUCK / 2];       //   512 B packed u16 hist
  __shared__ float4 kbox[TOPK];                  // 3,200 B kept boxes
  __shared__ alignas(16) float karr[TOPK];       //   800 B kept areas
  __shared__ float  kscore[TOPK];                //   800 B kept scores
  __shared__ int sh_nk;                          // block-consistent kept count
  __shared__ int sh_ctr;                         // compaction position counter

  // class-0 rows are all zeros: handled by the c1==0 block of each image
  if (c1 == 0) {
    float* o0 = out + (size_t)b * NCLS * TOPK * 5;
    for (int i = tid; i < TOPK * 5; i += 128) o0[i] = 0.0f;
  }

  for (int i = tid; i < NBUCK / 2; i += 128) hist[i] = 0u;
  if (tid == 0) sh_nk = 0;
  __syncthreads();

  const float* myF = conf + (size_t)b * NPRI * NCLS + c;
  const float4* myL = (const float4*)loc + (size_t)b * NPRI;
  const float4* pri4 = (const float4*)priors;

  // ---- histogram over thresholded score bits, j-space split by wave ----
  for (int k = w; k < ELTS; k += 2) {
    const int j = k * 64 + lane;
    unsigned int bits = 0u;
    if (j < NPRI) {
      float s = myF[(size_t)j * NCLS];
      bits = (s > CONF_T) ? __float_as_uint(s) : 0u;
    }
    if (bits) {
      unsigned int bu = (bits - BITS_BASE) >> BSHIFT;   // 8..223
      atomicAdd(&hist[bu >> 1], 1u << ((bu & 1) * 16));
    }
  }
  __syncthreads();

  float* obase = out + ((size_t)b * NCLS + c) * (TOPK * 5);
  int cutHiB = NUSED;

  for (;;) {
    // round head: sh_nk last written before a barrier -> both waves agree
    if (sh_nk >= TOPK || cutHiB <= 0) break;

    // ---- pick batch (both waves redundantly, identical result) ----
    int sl = 0;
#pragma unroll
    for (int t = 0; t < 4; ++t) {
      int bu = lane * 4 + t;
      if (bu < cutHiB) sl += (int)((hist[bu >> 1] >> ((bu & 1) * 16)) & 0xFFFFu);
    }
    int suf = sl;
#pragma unroll
    for (int d = 1; d < 64; d <<= 1) {
      int v = __shfl_down(suf, d, 64);
      if (lane + d < 64) suf += v;
    }
    unsigned long long m = __ballot(suf <= CAP);
    int Ls = (m != 0ull) ? __builtin_ctzll(m) : 63;
    int cutLoB = Ls * 4;
    if (cutLoB >= cutHiB) cutLoB = (cutHiB - 1) & ~3;   // degenerate, P~0
    const unsigned int loBits = BITS_BASE + ((unsigned)cutLoB << BSHIFT);
    const unsigned int hiBits = BITS_BASE + ((unsigned)cutHiB << BSHIFT);

    // ---- compact batch members; position via shared atomic (order is
    //      irrelevant: keys unique, sort follows) ----
    if (tid == 0) sh_ctr = 0;
    for (int t = tid; t < CAP; t += 128) skey[t] = 0ull;
    __syncthreads();

    for (int k = w; k < ELTS; k += 2) {
      const int j = k * 64 + lane;
      unsigned int bits = 0u;
      if (j < NPRI) {
        float s = myF[(size_t)j * NCLS];
        bits = (s > CONF_T) ? __float_as_uint(s) : 0u;
      }
      bool sel = (bits >= loBits) && (bits < hiBits);
      unsigned long long bm = __ballot(sel);
      int cnt = (int)__popcll(bm);
      int wb = 0;
      if (lane == 0 && cnt) wb = atomicAdd(&sh_ctr, cnt);
      wb = __builtin_amdgcn_readfirstlane(wb);
      if (sel) {
        int pos = wb + (int)__popcll(bm & ((1ull << lane) - 1ull));
        if (pos < CAP)
          skey[pos] = ((unsigned long long)bits << 12) | (unsigned)(4095 - j);
      }
    }
    __syncthreads();
    int Nc = sh_ctr;
    if (Nc > CAP) Nc = CAP;

    if (Nc > 0) {
      // ---- bitonic sort descending, 128 threads, 1 pair/thread/pass.
      //      jj<=64 passes stay inside one wave's half; only jj=128 crosses
      //      waves -> 2 barriers mid-sort + 1 post-sort (round-10 fix). ----
      for (int kk = 2; kk <= CAP; kk <<= 1) {
        for (int jj = kk >> 1; jj > 0; jj >>= 1) {
          if (jj == 128) __syncthreads();   // about to read across halves
          int i = ((tid & ~(jj - 1)) << 1) | (tid & (jj - 1));
          int ixj = i | jj;
          unsigned long long a = skey[i], d = skey[ixj];
          bool up = (i & kk) == 0;
          if (up ? (a < d) : (a > d)) { skey[i] = d; skey[ixj] = a; }
          if (jj == 128) __syncthreads();   // cross-half writes visible
          else __threadfence_block();       // same-wave DS in-order
        }
      }
      __syncthreads();

      // ---- tile-pair scan: wave w dense-tests tile 2p+w vs the kept
      //      snapshot in parallel; serial resolution stays in order ----
      for (int p0 = 0;; p0 += 128) {
        if (p0 >= Nc) break;
        const int nk0 = sh_nk;            // post-barrier consistent snapshot
        if (nk0 >= TOPK) break;

        const int p = p0 + w * 64 + lane;
        const bool valid = p < Nc;
        unsigned long long key = valid ? skey[p] : 0ull;
        unsigned int bits = (unsigned int)(key >> 12);
        int j = 4095 - (int)(key & 4095ull);

        // ---- fused decode-on-gather (bit-identical to old decode kernel:
        //      same op order, same expf) ----
        const int jg = valid ? j : 0;
        const float4 l4 = myL[jg];
        const float4 pp = pri4[jg];
        float cx = pp.x + (l4.x * 0.1f) * pp.z;
        float cy = pp.y + (l4.y * 0.1f) * pp.w;
        float bw = pp.z * expf(l4.z * 0.2f);
        float bh = pp.w * expf(l4.w * 0.2f);
        float4 bx = make_float4(cx - bw * 0.5f, cy - bh * 0.5f,
                                cx + bw * 0.5f, cy + bh * 0.5f);
        float carea = (bx.z - bx.x) * (bx.w - bx.y);

        // dense vs kept[0..nk0): float-max suppression accumulator
        // (m>0 <=> suppressed; exactly OR of per-kept predicates).
        float fm = valid ? -1.0f : 1.0f;   // padding pre-suppressed
        int s = 0;
        for (; s + 3 < nk0; s += 4) {
          float4 k0 = kbox[s];     float4 k1 = kbox[s + 1];
          float4 k2 = kbox[s + 2]; float4 k3 = kbox[s + 3];
          float4 ar = *(const float4*)&karr[s];   // one ds_read_b128
          float v01 = fmaxf(iou_val(k0, ar.x, bx, carea),
                            iou_val(k1, ar.y, bx, carea));
          float v23 = fmaxf(iou_val(k2, ar.z, bx, carea),
                            iou_val(k3, ar.w, bx, carea));
          fm = fmaxf(fm, fmaxf(v01, v23));
          if (__ballot(fm > 0.0f) == ~0ull) { s = nk0; break; }
        }
        for (; s < nk0; ++s)
          fm = fmaxf(fm, iou_val(kbox[s], karr[s], bx, carea));
        unsigned long long smask = __ballot(fm > 0.0f);

        if (w == 0) {   // resolve tile 2p (writes kbox[nk0..), disjoint from
                        // wave 1's concurrent reads of kbox[0..nk0))
          int nk = resolve_tile(smask, bx, carea, bits, lane, nk0,
                                kbox, karr, kscore);
          if (lane == 0) sh_nk = nk;
        }
        __syncthreads();
        if (w == 1) {   // catch-up vs keeps added by tile 2p, then resolve
          const int nk1 = sh_nk;
          for (int s2 = nk0; s2 < nk1; ++s2) {
            smask |= __ballot(iou_sup(kbox[s2], karr[s2], bx, carea));
            if (smask == ~0ull) break;
          }
          int nk = resolve_tile(smask, bx, carea, bits, lane, nk1,
                                kbox, karr, kscore);
          if (lane == 0) sh_nk = nk;
        }
        __syncthreads();
      }
    }
    cutHiB = cutLoB;
  }

  // ---- coalesced output dump: rows (score,x1,y1,x2,y2), zeros past nk ----
  __syncthreads();
  const int nkf = sh_nk;
  const float* kbf = (const float*)&kbox[0];
  for (int i = tid; i < TOPK * 5; i += 128) {
    int r = i / 5;
    int col = i - r * 5;
    float v = 0.0f;
    if (r < nkf) v = (col == 0) ? kscore[r] : kbf[r * 4 + (col - 1)];
    obase[i] = v;
  }
}

extern "C" void kernel_launch(void* const* d_in, const int* in_sizes, int n_in,
                              void* d_out, int out_size, void* d_ws, size_t ws_size,
                              hipStream_t stream) {
  const float* loc    = (const float*)d_in[0];
  const float* conf   = (const float*)d_in[1];
  const float* priors = (const float*)d_in[2];
  float* out = (float*)d_out;
  (void)d_ws; (void)ws_size;          // workspace no longer needed

  const int batch = in_sizes[0] / (NPRI * 4);
  hipLaunchKernelGGL(ssd_nms_kernel, dim3(batch * 20), dim3(128), 0, stream,
                     loc, conf, priors, out, batch);
}

// Round 11
// 417.986 us; speedup vs baseline: 1.1973x; 1.0078x over previous
//
#include <hip/hip_runtime.h>
#include <math.h>

// SSDLite post-processing, round 18 = round 17 (fused single-kernel, 360us
// dispatch) + one-pass bucket-sorted index list replacing the per-round
// compaction re-scan.
// Rationale: each of ~12 rounds re-scanned the full conf column (24 strided
// iters x ~14 instr with a serial ballot->popc->LDS-atomic->readfirstlane
// chain) to extract ~250 range members. Now: after the histogram, wave 0
// prefix-scans the 224 bucket counts (pfx[], LDS u16); both waves scatter
// each passing prior's j (u16) into a GLOBAL bucket-sorted list (30.7 MB
// workspace; ws>=73.7MB proven available in round 8) at atomicAdd(ctr[bu])
// seeded from pfx. Per round: slice bounds from pfx (also replaces the
// 6-step shuffle suffix-scan in batch-pick -- identical Ls by construction),
// coalesced u16 slice read + score re-gather to form keys. Non-degenerate
// rounds pick the SAME candidate set; the bitonic sort makes within-bucket
// insertion order irrelevant -> identical sorted sequence, bit-identical
// downstream. Barriers 10 -> 8 per round. Legacy compaction kept as a
// runtime fallback if ws_size is too small.
// Everything else byte-identical to round 17: 2-wave coop class blocks
// (grid=batch*20, 128 thr, 16 blk/CU = 32 waves phase-1), XCD swizzle,
// fused decode-on-gather, float-max dense accumulator + karr ds_read_b128,
// M-refilter resolve, exact 2x-fma IoU predicate.

#define NCLS 21
#define TOPK 200
#define NPRI 3000
#define ELTS 47            // ceil(3000/64)
#define CONF_T 0.01f
#define MHI 0.45f
#define MLO 1.490116119384765625e-08f   // 2^-26 == ulp(0.45f)/2
#define CAP 256            // sort/batch capacity
#define NBUCK 256          // histogram buckets (224 used)
#define NUSED 224
#define BITS_BASE 0x3C000000u           // bits(2^-7); 0.01 > 2^-7
#define BSHIFT 18

__device__ __forceinline__ float rdlf(float v, int l) {
  return __int_as_float(__builtin_amdgcn_readlane(__float_as_int(v), l));
}

// IoU suppression VALUE: >0 means suppressed. EXACT reference numerics
// (2x fma, MLO half-ulp nudge); 'a' = kept-box area everywhere.
__device__ __forceinline__ float iou_val(const float4 k, const float a,
                                         const float4 b, const float carea) {
  float ltx = fmaxf(k.x, b.x), lty = fmaxf(k.y, b.y);
  float rbx = fminf(k.z, b.z), rby = fminf(k.w, b.w);
  float iw = fmaxf(rbx - ltx, 0.0f), ih = fmaxf(rby - lty, 0.0f);
  float inter = iw * ih;
  float uni = (a + carea) - inter;
  return fmaf(-MLO, uni, fmaf(-MHI, uni, inter));
}

__device__ __forceinline__ bool iou_sup(const float4 k, const float a,
                                        const float4 b, const float carea) {
  return iou_val(k, a, b, carea) > 0.0f;
}

// M-refilter keep-resolution (round 15). Pop lowest survivor (guaranteed
// keepable), broadcast, prune M by one parallel iou. Sequential-identical.
__device__ __forceinline__ int resolve_tile(
    unsigned long long smask, const float4 bx, const float carea,
    const unsigned int bits, const int lane, int nk,
    float4* kbox, float* karr, float* kscore) {
  unsigned long long M = ~smask;
  while (M && nk < TOPK) {
    const int ls = (int)__builtin_ctzll(M);
    const float sx1 = rdlf(bx.x, ls), sy1 = rdlf(bx.y, ls);
    const float sx2 = rdlf(bx.z, ls), sy2 = rdlf(bx.w, ls);
    const float sar = rdlf(carea, ls);
    const unsigned int sbits =
        (unsigned int)__builtin_amdgcn_readlane((int)bits, ls);
    const float4 nb = make_float4(sx1, sy1, sx2, sy2);
    if (lane == 0) {
      kbox[nk]   = nb;
      karr[nk]   = sar;
      kscore[nk] = __uint_as_float(sbits);
    }
    ++nk;
    // prune remaining survivors by the newly kept box (self included: iou=1)
    M &= ~__ballot(iou_val(nb, sar, bx, carea) > 0.0f);
    M &= ~(1ull << ls);
  }
  return nk;
}

__global__ __launch_bounds__(128, 8) void ssd_nms_kernel(
    const float* __restrict__ loc, const float* __restrict__ conf,
    const float* __restrict__ priors, float* __restrict__ out,
    unsigned short* __restrict__ jlist, int nbatch, int useL) {
  const int blk = blockIdx.x;
  int b, c1;
  if ((nbatch & 7) == 0) {
    // XCD swizzle: image b's 20 class-blocks land on XCD b&7 -> the image's
    // conf/loc slabs stay in one XCD's L2.
    const int xcd  = blk & 7;
    const int rest = blk >> 3;
    b  = (rest / 20) * 8 + xcd;
    c1 = rest % 20;
  } else {
    b  = blk / 20;
    c1 = blk % 20;
  }
  const int c    = 1 + c1;            // class in [1,20]
  const int tid  = threadIdx.x;
  const int lane = tid & 63;
  const int w    = tid >> 6;          // wave in block (2 waves, one class)

  __shared__ unsigned long long skey[CAP];       // 2,048 B sort buf
  __shared__ unsigned int hist[NBUCK / 2];       //   512 B packed u16 hist
  __shared__ unsigned short pfx[NUSED + 2];      //   452 B bucket prefix sums
  __shared__ unsigned int ctr[NUSED];            //   896 B scatter cursors
  __shared__ float4 kbox[TOPK];                  // 3,200 B kept boxes
  __shared__ alignas(16) float karr[TOPK];       //   800 B kept areas
  __shared__ float  kscore[TOPK];                //   800 B kept scores
  __shared__ int sh_nk;                          // block-consistent kept count
  __shared__ int sh_ctr;                         // fallback compaction counter

  // class-0 rows are all zeros: handled by the c1==0 block of each image
  if (c1 == 0) {
    float* o0 = out + (size_t)b * NCLS * TOPK * 5;
    for (int i = tid; i < TOPK * 5; i += 128) o0[i] = 0.0f;
  }

  for (int i = tid; i < NBUCK / 2; i += 128) hist[i] = 0u;
  if (tid == 0) sh_nk = 0;
  __syncthreads();

  const float* myF = conf + (size_t)b * NPRI * NCLS + c;
  const float4* myL = (const float4*)loc + (size_t)b * NPRI;
  const float4* pri4 = (const float4*)priors;
  unsigned short* jl = jlist + ((size_t)b * 20 + c1) * NPRI;

  // ---- histogram over thresholded score bits, j-space split by wave ----
  for (int k = w; k < ELTS; k += 2) {
    const int j = k * 64 + lane;
    unsigned int bits = 0u;
    if (j < NPRI) {
      float s = myF[(size_t)j * NCLS];
      bits = (s > CONF_T) ? __float_as_uint(s) : 0u;
    }
    if (bits) {
      unsigned int bu = (bits - BITS_BASE) >> BSHIFT;   // 8..223
      atomicAdd(&hist[bu >> 1], 1u << ((bu & 1) * 16));
    }
  }
  __syncthreads();

  if (useL) {
    // ---- one-time: prefix-scan bucket counts (wave 0) ----
    if (w == 0) {
      const int bu0 = lane * 4;
      int c0 = 0, c1x = 0, c2 = 0, c3 = 0;
      if (bu0 < NUSED) {
        unsigned int h0 = hist[lane * 2];
        unsigned int h1 = hist[lane * 2 + 1];
        c0 = (int)(h0 & 0xFFFFu); c1x = (int)(h0 >> 16);
        c2 = (int)(h1 & 0xFFFFu); c3 = (int)(h1 >> 16);
      }
      const int sl = c0 + c1x + c2 + c3;
      int incl = sl;
#pragma unroll
      for (int d = 1; d < 64; d <<= 1) {
        int v = __shfl_up(incl, d, 64);
        if (lane >= d) incl += v;
      }
      const int excl = incl - sl;
      if (bu0 < NUSED) {
        pfx[bu0]     = (unsigned short)excl;
        pfx[bu0 + 1] = (unsigned short)(excl + c0);
        pfx[bu0 + 2] = (unsigned short)(excl + c0 + c1x);
        pfx[bu0 + 3] = (unsigned short)(excl + c0 + c1x + c2);
      }
      if (lane == 56) pfx[NUSED] = (unsigned short)excl;   // total
    }
    __syncthreads();
    for (int i = tid; i < NUSED; i += 128) ctr[i] = pfx[i];
    __syncthreads();

    // ---- one-time: scatter passing priors into the bucket-sorted list ----
    for (int k = w; k < ELTS; k += 2) {
      const int j = k * 64 + lane;
      if (j < NPRI) {
        float s = myF[(size_t)j * NCLS];
        if (s > CONF_T) {
          unsigned int bits = __float_as_uint(s);
          unsigned int bu = (bits - BITS_BASE) >> BSHIFT;
          unsigned int pos = atomicAdd(&ctr[bu], 1u);
          jl[pos] = (unsigned short)j;
        }
      }
    }
    __syncthreads();   // list writes visible block-wide before round reads
  }

  float* obase = out + ((size_t)b * NCLS + c) * (TOPK * 5);
  int cutHiB = NUSED;

  for (;;) {
    // round head: sh_nk last written before a barrier -> both waves agree
    if (sh_nk >= TOPK || cutHiB <= 0) break;

    int Nc, lo = 0;
    int cutLoB;
    if (useL) {
      // ---- batch pick via prefix sums (identical Ls to suffix-scan) ----
      const int bu = lane * 4;
      int suf = 0;
      if (bu < cutHiB) suf = (int)pfx[cutHiB] - (int)pfx[bu];
      unsigned long long m = __ballot(suf <= CAP);
      int Ls = (m != 0ull) ? __builtin_ctzll(m) : 63;
      cutLoB = Ls * 4;
      if (cutLoB >= cutHiB) cutLoB = (cutHiB - 1) & ~3;   // degenerate, P~0
      lo = (int)pfx[cutLoB];
      Nc = (int)pfx[cutHiB] - lo;
      if (Nc > CAP) Nc = CAP;

      if (Nc > 0) {
        // ---- fill sort buffer straight from the list slice ----
        for (int t = tid; t < CAP; t += 128) {
          unsigned long long key = 0ull;
          if (t < Nc) {
            const int j = (int)jl[lo + t];
            const unsigned int bits = __float_as_uint(myF[(size_t)j * NCLS]);
            key = ((unsigned long long)bits << 12) | (unsigned)(4095 - j);
          }
          skey[t] = key;
        }
        __syncthreads();
      }
    } else {
      // ---- fallback: legacy suffix-scan batch pick + compaction scan ----
      int sl = 0;
#pragma unroll
      for (int t = 0; t < 4; ++t) {
        int bu = lane * 4 + t;
        if (bu < cutHiB) sl += (int)((hist[bu >> 1] >> ((bu & 1) * 16)) & 0xFFFFu);
      }
      int suf = sl;
#pragma unroll
      for (int d = 1; d < 64; d <<= 1) {
        int v = __shfl_down(suf, d, 64);
        if (lane + d < 64) suf += v;
      }
      unsigned long long m = __ballot(suf <= CAP);
      int Ls = (m != 0ull) ? __builtin_ctzll(m) : 63;
      cutLoB = Ls * 4;
      if (cutLoB >= cutHiB) cutLoB = (cutHiB - 1) & ~3;
      const unsigned int loBits = BITS_BASE + ((unsigned)cutLoB << BSHIFT);
      const unsigned int hiBits = BITS_BASE + ((unsigned)cutHiB << BSHIFT);

      if (tid == 0) sh_ctr = 0;
      for (int t = tid; t < CAP; t += 128) skey[t] = 0ull;
      __syncthreads();
      for (int k = w; k < ELTS; k += 2) {
        const int j = k * 64 + lane;
        unsigned int bits = 0u;
        if (j < NPRI) {
          float s = myF[(size_t)j * NCLS];
          bits = (s > CONF_T) ? __float_as_uint(s) : 0u;
        }
        bool sel = (bits >= loBits) && (bits < hiBits);
        unsigned long long bm = __ballot(sel);
        int cnt = (int)__popcll(bm);
        int wb = 0;
        if (lane == 0 && cnt) wb = atomicAdd(&sh_ctr, cnt);
        wb = __builtin_amdgcn_readfirstlane(wb);
        if (sel) {
          int pos = wb + (int)__popcll(bm & ((1ull << lane) - 1ull));
          if (pos < CAP)
            skey[pos] = ((unsigned long long)bits << 12) | (unsigned)(4095 - j);
        }
      }
      __syncthreads();
      Nc = sh_ctr;
      if (Nc > CAP) Nc = CAP;
    }

    if (Nc > 0) {
      // ---- bitonic sort descending, 128 threads, 1 pair/thread/pass.
      //      jj<=64 passes stay inside one wave's half; only jj=128 crosses
      //      waves -> 2 barriers mid-sort + 1 post-sort (round-10 fix). ----
      for (int kk = 2; kk <= CAP; kk <<= 1) {
        for (int jj = kk >> 1; jj > 0; jj >>= 1) {
          if (jj == 128) __syncthreads();   // about to read across halves
          int i = ((tid & ~(jj - 1)) << 1) | (tid & (jj - 1));
          int ixj = i | jj;
          unsigned long long a = skey[i], d = skey[ixj];
          bool up = (i & kk) == 0;
          if (up ? (a < d) : (a > d)) { skey[i] = d; skey[ixj] = a; }
          if (jj == 128) __syncthreads();   // cross-half writes visible
          else __threadfence_block();       // same-wave DS in-order
        }
      }
      __syncthreads();

      // ---- tile-pair scan: wave w dense-tests tile 2p+w vs the kept
      //      snapshot in parallel; serial resolution stays in order ----
      for (int p0 = 0;; p0 += 128) {
        if (p0 >= Nc) break;
        const int nk0 = sh_nk;            // post-barrier consistent snapshot
        if (nk0 >= TOPK) break;

        const int p = p0 + w * 64 + lane;
        const bool valid = p < Nc;
        unsigned long long key = valid ? skey[p] : 0ull;
        unsigned int bits = (unsigned int)(key >> 12);
        int j = 4095 - (int)(key & 4095ull);

        // ---- fused decode-on-gather (bit-identical to reference order) ----
        const int jg = valid ? j : 0;
        const float4 l4 = myL[jg];
        const float4 pp = pri4[jg];
        float cx = pp.x + (l4.x * 0.1f) * pp.z;
        float cy = pp.y + (l4.y * 0.1f) * pp.w;
        float bw = pp.z * expf(l4.z * 0.2f);
        float bh = pp.w * expf(l4.w * 0.2f);
        float4 bx = make_float4(cx - bw * 0.5f, cy - bh * 0.5f,
                                cx + bw * 0.5f, cy + bh * 0.5f);
        float carea = (bx.z - bx.x) * (bx.w - bx.y);

        // dense vs kept[0..nk0): float-max suppression accumulator
        // (m>0 <=> suppressed; exactly OR of per-kept predicates).
        float fm = valid ? -1.0f : 1.0f;   // padding pre-suppressed
        int s = 0;
        for (; s + 3 < nk0; s += 4) {
          float4 k0 = kbox[s];     float4 k1 = kbox[s + 1];
          float4 k2 = kbox[s + 2]; float4 k3 = kbox[s + 3];
          float4 ar = *(const float4*)&karr[s];   // one ds_read_b128
          float v01 = fmaxf(iou_val(k0, ar.x, bx, carea),
                            iou_val(k1, ar.y, bx, carea));
          float v23 = fmaxf(iou_val(k2, ar.z, bx, carea),
                            iou_val(k3, ar.w, bx, carea));
          fm = fmaxf(fm, fmaxf(v01, v23));
          if (__ballot(fm > 0.0f) == ~0ull) { s = nk0; break; }
        }
        for (; s < nk0; ++s)
          fm = fmaxf(fm, iou_val(kbox[s], karr[s], bx, carea));
        unsigned long long smask = __ballot(fm > 0.0f);

        if (w == 0) {   // resolve tile 2p (writes kbox[nk0..), disjoint from
                        // wave 1's concurrent reads of kbox[0..nk0))
          int nk = resolve_tile(smask, bx, carea, bits, lane, nk0,
                                kbox, karr, kscore);
          if (lane == 0) sh_nk = nk;
        }
        __syncthreads();
        if (w == 1) {   // catch-up vs keeps added by tile 2p, then resolve
          const int nk1 = sh_nk;
          for (int s2 = nk0; s2 < nk1; ++s2) {
            smask |= __ballot(iou_sup(kbox[s2], karr[s2], bx, carea));
            if (smask == ~0ull) break;
          }
          int nk = resolve_tile(smask, bx, carea, bits, lane, nk1,
                                kbox, karr, kscore);
          if (lane == 0) sh_nk = nk;
        }
        __syncthreads();
      }
    }
    cutHiB = cutLoB;
  }

  // ---- coalesced output dump: rows (score,x1,y1,x2,y2), zeros past nk ----
  __syncthreads();
  const int nkf = sh_nk;
  const float* kbf = (const float*)&kbox[0];
  for (int i = tid; i < TOPK * 5; i += 128) {
    int r = i / 5;
    int col = i - r * 5;
    float v = 0.0f;
    if (r < nkf) v = (col == 0) ? kscore[r] : kbf[r * 4 + (col - 1)];
    obase[i] = v;
  }
}

extern "C" void kernel_launch(void* const* d_in, const int* in_sizes, int n_in,
                              void* d_out, int out_size, void* d_ws, size_t ws_size,
                              hipStream_t stream) {
  const float* loc    = (const float*)d_in[0];
  const float* conf   = (const float*)d_in[1];
  const float* priors = (const float*)d_in[2];
  float* out = (float*)d_out;

  const int batch = in_sizes[0] / (NPRI * 4);
  unsigned short* jlist = (unsigned short*)d_ws;
  const size_t need = (size_t)batch * 20 * NPRI * sizeof(unsigned short);
  const int useL = (d_ws != nullptr && ws_size >= need) ? 1 : 0;  // 30.7 MB

  hipLaunchKernelGGL(ssd_nms_kernel, dim3(batch * 20), dim3(128), 0, stream,
                     loc, conf, priors, out, jlist, batch, useL);
}